// Round 3
// baseline (194.524 us; speedup 1.0000x reference)
//
#include <hip/hip_runtime.h>

#define BTOT 1000000
#define NCHUNK (BTOT / 64)   // 15625 chunks of 64 elements

typedef _Float16 f16;
typedef f16 f16x2 __attribute__((ext_vector_type(2)));
typedef f16 f16x8 __attribute__((ext_vector_type(8)));
typedef float f32x4 __attribute__((ext_vector_type(4)));

// d_ws layout (bytes) — written by setup_kernel, read coalesced by netc_kernel:
//   0     : float u_tgt
//   16    : bfragT[8][64]  f16x8   (8192 B)   item = n*2+ks
//   8208  : w1aT [8][64]   f16x2   (2048 B)
//   10256 : w1bT [8][64]   f16x2   (2048 B)
//   12304 : b1pT [8][64]   f16x2   (2048 B)
//   14352 : w3vT [4][64]   float   (1024 B)
//   15376 : b2vT [4][64]   float   (1024 B)
#define WS_BFRAG 16
#define WS_W1A   8208
#define WS_W1B   10256
#define WS_B1P   12304
#define WS_W3V   14352
#define WS_B2V   15376

// 16-lane-row rotate-and-add via DPP (VALU pipe, no LDS traffic).
template<int CTRL>
__device__ __forceinline__ float dpp_add(float v) {
    int pv = __builtin_amdgcn_update_dpp(0, __builtin_bit_cast(int, v),
                                         CTRL, 0xF, 0xF, true);
    return v + __builtin_bit_cast(float, pv);
}

// One block. Stages W2 coalesced through padded LDS (conflict-free reads),
// computes u(target) once, emits per-lane register images into ws.
__global__ __launch_bounds__(256) void setup_kernel(
    const float* __restrict__ W1, const float* __restrict__ b1,
    const float* __restrict__ W2, const float* __restrict__ b2,
    const float* __restrict__ W3, unsigned char* __restrict__ ws)
{
    const int tid  = threadIdx.x;
    const int quad = (tid & 63) >> 4;
    const int nl   = tid & 15;

    __shared__ float w2s[64 * 65];   // padded: row stride 65 -> conflict-free
    __shared__ float h1s[64];
    __shared__ float part[4 * 64];

    // coalesced W2 -> LDS (each float4 stays within one 64-elem row)
    const float4* W2v = (const float4*)W2;
    #pragma unroll
    for (int r = 0; r < 4; ++r) {
        int idx = r * 256 + tid;           // 1024 float4s total
        float4 f = W2v[idx];
        int g = idx * 4, row = g >> 6, col = g & 63;
        float* p = &w2s[row * 65 + col];
        p[0] = f.x; p[1] = f.y; p[2] = f.z; p[3] = f.w;
    }
    const float T = 6.2562059f;  // 0.62562059 * 10
    if (tid < 64)
        h1s[tid] = fmaxf(0.f, W1[2 * tid] * T + W1[2 * tid + 1] * T + b1[tid]);
    __syncthreads();

    // u_tgt: thread t does rows r=t&63, k-quarter t>>6
    {
        int r = tid & 63, kq = tid >> 6;
        float p = 0.f;
        #pragma unroll
        for (int k = 0; k < 16; ++k)
            p = fmaf(w2s[r * 65 + kq * 16 + k], h1s[kq * 16 + k], p);
        part[kq * 64 + r] = p;
    }
    __syncthreads();
    if (tid < 64) {
        float h2 = b2[tid] + part[tid] + part[64 + tid] + part[128 + tid] + part[192 + tid];
        float pr = fmaxf(0.f, h2) * W3[tid];
        #pragma unroll
        for (int m = 1; m < 64; m <<= 1) pr += __shfl_xor(pr, m, 64);
        if (tid == 0) *(float*)ws = pr;
    }

    if (tid < 64) {   // lane = tid: build this lane's register images
        f16x8* bfragT = (f16x8*)(ws + WS_BFRAG);
        #pragma unroll
        for (int n = 0; n < 4; ++n)
            #pragma unroll
            for (int ks = 0; ks < 2; ++ks) {
                f16x8 f;
                #pragma unroll
                for (int j = 0; j < 8; ++j)
                    f[j] = (f16)w2s[(n * 16 + nl) * 65 + ks * 32 + quad * 8 + j];
                bfragT[(n * 2 + ks) * 64 + tid] = f;
            }
        f16x2* w1aT = (f16x2*)(ws + WS_W1A);
        f16x2* w1bT = (f16x2*)(ws + WS_W1B);
        f16x2* b1pT = (f16x2*)(ws + WS_B1P);
        #pragma unroll
        for (int i = 0; i < 8; ++i) {
            int kk = (i < 4) ? (quad * 8 + 2 * i) : (32 + quad * 8 + 2 * (i - 4));
            w1aT[i * 64 + tid] = f16x2{(f16)W1[2 * kk],     (f16)W1[2 * kk + 2]};
            w1bT[i * 64 + tid] = f16x2{(f16)W1[2 * kk + 1], (f16)W1[2 * kk + 3]};
            b1pT[i * 64 + tid] = f16x2{(f16)b1[kk],         (f16)b1[kk + 1]};
        }
        float* w3vT = (float*)(ws + WS_W3V);
        float* b2vT = (float*)(ws + WS_B2V);
        #pragma unroll
        for (int n = 0; n < 4; ++n) {
            w3vT[n * 64 + tid] = W3[n * 16 + nl];
            b2vT[n * 64 + tid] = b2[n * 16 + nl];
        }
    }
}

__global__ __launch_bounds__(256, 4) void netc_kernel(
    const float* __restrict__ x,  const float* __restrict__ y,
    const float* __restrict__ ex, const float* __restrict__ ey,
    const unsigned char* __restrict__ ws,
    float* __restrict__ out)
{
    const int tid  = threadIdx.x;
    const int lane = tid & 63;
    const int wv   = tid >> 6;
    const int quad = lane >> 4;
    const int nl   = lane & 15;

    // ---------- preamble: ~40 fully-coalesced loads, no LDS ----------
    const float u_tgt = *(const float*)ws;   // wave-uniform -> scalar load
    const f16x8* bfragT = (const f16x8*)(ws + WS_BFRAG);
    f16x8 bfrag[4][2];
    #pragma unroll
    for (int n = 0; n < 4; ++n)
        #pragma unroll
        for (int ks = 0; ks < 2; ++ks)
            bfrag[n][ks] = bfragT[(n * 2 + ks) * 64 + lane];
    const f16x2* w1aT = (const f16x2*)(ws + WS_W1A);
    const f16x2* w1bT = (const f16x2*)(ws + WS_W1B);
    const f16x2* b1pT = (const f16x2*)(ws + WS_B1P);
    f16x2 w1a[8], w1b[8], b1p[8];
    #pragma unroll
    for (int i = 0; i < 8; ++i) {
        w1a[i] = w1aT[i * 64 + lane];
        w1b[i] = w1bT[i * 64 + lane];
        b1p[i] = b1pT[i * 64 + lane];
    }
    const float* w3vT = (const float*)(ws + WS_W3V);
    const float* b2vT = (const float*)(ws + WS_B2V);
    float w3v[4], b2v[4];
    #pragma unroll
    for (int n = 0; n < 4; ++n) { w3v[n] = w3vT[n * 64 + lane]; b2v[n] = b2vT[n * 64 + lane]; }

    const f16x2 zero2 = {(f16)0.f, (f16)0.f};
    const int nwaves = (gridDim.x * blockDim.x) >> 6;
    int chunk = (blockIdx.x << 2) + wv;

    // Gather loads in MFMA A-layout: lane reads element chunk*64 + t*16 + nl
    // (4-way broadcast across quads, 256B window -> L1). Lane-layout x,y for
    // the Hill math recovered with a 3-cndmask quad-select.
    float xg[4], yg[4], exg[4], eyg[4];
    if (chunk < NCHUNK) {
        #pragma unroll
        for (int t = 0; t < 4; ++t) {
            int a = chunk * 64 + t * 16 + nl;
            xg[t] = x[a]; yg[t] = y[a]; exg[t] = ex[a]; eyg[t] = ey[a];
        }
    }

    for (; chunk < NCHUNK; chunk += nwaves) {
        float ag[4], bg[4];
        #pragma unroll
        for (int t = 0; t < 4; ++t) { ag[t] = xg[t] + exg[t]; bg[t] = yg[t] + eyg[t]; }
        float cx0 = (quad & 1) ? xg[1] : xg[0];
        float cx1 = (quad & 1) ? xg[3] : xg[2];
        float cx  = (quad & 2) ? cx1 : cx0;
        float cy0 = (quad & 1) ? yg[1] : yg[0];
        float cy1 = (quad & 1) ? yg[3] : yg[2];
        float cy  = (quad & 2) ? cy1 : cy0;

        // prefetch next iter
        int nxt = chunk + nwaves;
        float nx_[4] = {0,0,0,0}, ny_[4] = {0,0,0,0}, nex_[4] = {0,0,0,0}, ney_[4] = {0,0,0,0};
        if (nxt < NCHUNK) {
            #pragma unroll
            for (int t = 0; t < 4; ++t) {
                int a = nxt * 64 + t * 16 + nl;
                nx_[t] = x[a]; ny_[t] = y[a]; nex_[t] = ex[a]; ney_[t] = ey[a];
            }
        }

        // accumulators pre-loaded with b2 (column-constant)
        f32x4 acc[4][4];
        #pragma unroll
        for (int t = 0; t < 4; ++t)
            #pragma unroll
            for (int n = 0; n < 4; ++n)
                acc[t][n] = f32x4{b2v[n], b2v[n], b2v[n], b2v[n]};

        #pragma unroll
        for (int t = 0; t < 4; ++t) {
            f16 ah = (f16)ag[t], bh = (f16)bg[t];
            f16x2 a2 = {ah, ah};
            f16x2 bb = {bh, bh};
            union { f16x2 h2[8]; f16x8 fr[2]; } u;
            #pragma unroll
            for (int i = 0; i < 8; ++i) {
                f16x2 h = a2 * w1a[i] + (bb * w1b[i] + b1p[i]);
                u.h2[i] = __builtin_elementwise_max(h, zero2);
            }
            #pragma unroll
            for (int n = 0; n < 4; ++n) {
                acc[t][n] = __builtin_amdgcn_mfma_f32_16x16x32_f16(u.fr[0], bfrag[n][0], acc[t][n], 0, 0, 0);
                acc[t][n] = __builtin_amdgcn_mfma_f32_16x16x32_f16(u.fr[1], bfrag[n][1], acc[t][n], 0, 0, 0);
            }
        }

        // ---------- epilogue: layer 3 via DPP row reductions ----------
        float uu[4][4];
        #pragma unroll
        for (int t = 0; t < 4; ++t)
            #pragma unroll
            for (int r = 0; r < 4; ++r) {
                float p = 0.f;
                #pragma unroll
                for (int n = 0; n < 4; ++n)
                    p = fmaf(fmaxf(acc[t][n][r], 0.f), w3v[n], p);
                p = dpp_add<0x128>(p);  // row_ror:8
                p = dpp_add<0x124>(p);  // row_ror:4
                p = dpp_add<0x122>(p);  // row_ror:2
                p = dpp_add<0x121>(p);  // row_ror:1
                uu[t][r] = p;
            }

        // sender lane s (p=s&15) provides uu[p>>2][p&3]
        float ur[4];
        #pragma unroll
        for (int t = 0; t < 4; ++t) {
            float v01 = (nl & 1) ? uu[t][1] : uu[t][0];
            float v23 = (nl & 1) ? uu[t][3] : uu[t][2];
            ur[t] = (nl & 2) ? v23 : v01;
        }
        float s01  = (nl & 4) ? ur[1] : ur[0];
        float s23  = (nl & 4) ? ur[3] : ur[2];
        float send = (nl & 8) ? s23 : s01;
        int srcLane = ((nl >> 2) << 4) + quad * 4 + (nl & 3);
        float u_e = __shfl(send, srcLane, 64) - u_tgt;

        // ---------- Hill kinetics (fp32) ----------
        float xs = cx * 0.1f, ys = cy * 0.1f;
        float x2 = xs * xs, y2 = ys * ys;
        float invx = __fdividef(1.0f, 0.25f + x2);
        float invy = __fdividef(1.0f, 0.25f + y2);
        float hx = x2 * invx, hy = y2 * invy;
        float gx = 0.25f * invx, gy = 0.25f * invy;
        float dx = 10.f * (fmaf(u_e, hx, hx) + 0.2f * gy - 1.1f * xs);
        float dy = 10.f * (hy + 0.2f * gx - 1.1f * ys);

        int e = chunk * 64 + lane;
        out[e]            = dx;
        out[BTOT + e]     = dy;
        out[2 * BTOT + e] = -dx;
        out[3 * BTOT + e] = -dy;

        #pragma unroll
        for (int t = 0; t < 4; ++t) {
            xg[t] = nx_[t]; yg[t] = ny_[t]; exg[t] = nex_[t]; eyg[t] = ney_[t];
        }
    }
}

extern "C" void kernel_launch(void* const* d_in, const int* in_sizes, int n_in,
                              void* d_out, int out_size, void* d_ws, size_t ws_size,
                              hipStream_t stream) {
    const float* x  = (const float*)d_in[0];
    const float* y  = (const float*)d_in[1];
    const float* ex = (const float*)d_in[2];
    const float* ey = (const float*)d_in[3];
    const float* W1 = (const float*)d_in[4];
    const float* b1 = (const float*)d_in[5];
    const float* W2 = (const float*)d_in[6];
    const float* b2 = (const float*)d_in[7];
    const float* W3 = (const float*)d_in[8];
    float* out = (float*)d_out;
    unsigned char* ws = (unsigned char*)d_ws;

    setup_kernel<<<1, 256, 0, stream>>>(W1, b1, W2, b2, W3, ws);
    // 1024 blocks x 256 threads = 4096 waves = 4 waves/SIMD resident
    netc_kernel<<<1024, 256, 0, stream>>>(x, y, ex, ey, ws, out);
}

// Round 4
// 132.678 us; speedup vs baseline: 1.4661x; 1.4661x over previous
//
#include <hip/hip_runtime.h>

#define BTOT 1000000
#define NCHUNK (BTOT / 64)   // 15625 chunks of 64 elements

typedef _Float16 f16;
typedef f16 f16x2 __attribute__((ext_vector_type(2)));
typedef f16 f16x8 __attribute__((ext_vector_type(8)));
typedef float f32x4 __attribute__((ext_vector_type(4)));

// d_ws layout (bytes) — written by setup_kernel, read coalesced by netc_kernel:
//   0     : float u_tgt
//   16    : bfragT[8][64]  f16x8   (8192 B)   item = n*2+ks
//   8208  : w1aT [8][64]   f16x2   (2048 B)
//   10256 : w1bT [8][64]   f16x2   (2048 B)
//   12304 : b1pT [8][64]   f16x2   (2048 B)
//   14352 : w3vT [4][64]   float   (1024 B)
//   15376 : b2vT [4][64]   float   (1024 B)
#define WS_BFRAG 16
#define WS_W1A   8208
#define WS_W1B   10256
#define WS_B1P   12304
#define WS_W3V   14352
#define WS_B2V   15376

// 16-lane-row rotate-and-add via DPP (VALU pipe, no LDS traffic).
template<int CTRL>
__device__ __forceinline__ float dpp_add(float v) {
    int pv = __builtin_amdgcn_update_dpp(0, __builtin_bit_cast(int, v),
                                         CTRL, 0xF, 0xF, true);
    return v + __builtin_bit_cast(float, pv);
}

// One block. Stages W2 coalesced through padded LDS (conflict-free reads),
// computes u(target) once, emits per-lane register images into ws.
__global__ __launch_bounds__(256) void setup_kernel(
    const float* __restrict__ W1, const float* __restrict__ b1,
    const float* __restrict__ W2, const float* __restrict__ b2,
    const float* __restrict__ W3, unsigned char* __restrict__ ws)
{
    const int tid  = threadIdx.x;
    const int quad = (tid & 63) >> 4;
    const int nl   = tid & 15;

    __shared__ float w2s[64 * 65];   // padded: row stride 65 -> conflict-free
    __shared__ float h1s[64];
    __shared__ float part[4 * 64];

    // coalesced W2 -> LDS (each float4 stays within one 64-elem row)
    const float4* W2v = (const float4*)W2;
    #pragma unroll
    for (int r = 0; r < 4; ++r) {
        int idx = r * 256 + tid;           // 1024 float4s total
        float4 f = W2v[idx];
        int g = idx * 4, row = g >> 6, col = g & 63;
        float* p = &w2s[row * 65 + col];
        p[0] = f.x; p[1] = f.y; p[2] = f.z; p[3] = f.w;
    }
    const float T = 6.2562059f;  // 0.62562059 * 10
    if (tid < 64)
        h1s[tid] = fmaxf(0.f, W1[2 * tid] * T + W1[2 * tid + 1] * T + b1[tid]);
    __syncthreads();

    // u_tgt: thread t does row r=t&63, k-quarter t>>6
    {
        int r = tid & 63, kq = tid >> 6;
        float p = 0.f;
        #pragma unroll
        for (int k = 0; k < 16; ++k)
            p = fmaf(w2s[r * 65 + kq * 16 + k], h1s[kq * 16 + k], p);
        part[kq * 64 + r] = p;
    }
    __syncthreads();
    if (tid < 64) {
        float h2 = b2[tid] + part[tid] + part[64 + tid] + part[128 + tid] + part[192 + tid];
        float pr = fmaxf(0.f, h2) * W3[tid];
        #pragma unroll
        for (int m = 1; m < 64; m <<= 1) pr += __shfl_xor(pr, m, 64);
        if (tid == 0) *(float*)ws = pr;
    }

    if (tid < 64) {   // lane = tid: build this lane's register images
        f16x8* bfragT = (f16x8*)(ws + WS_BFRAG);
        #pragma unroll
        for (int n = 0; n < 4; ++n)
            #pragma unroll
            for (int ks = 0; ks < 2; ++ks) {
                f16x8 f;
                #pragma unroll
                for (int j = 0; j < 8; ++j)
                    f[j] = (f16)w2s[(n * 16 + nl) * 65 + ks * 32 + quad * 8 + j];
                bfragT[(n * 2 + ks) * 64 + tid] = f;
            }
        f16x2* w1aT = (f16x2*)(ws + WS_W1A);
        f16x2* w1bT = (f16x2*)(ws + WS_W1B);
        f16x2* b1pT = (f16x2*)(ws + WS_B1P);
        #pragma unroll
        for (int i = 0; i < 8; ++i) {
            int kk = (i < 4) ? (quad * 8 + 2 * i) : (32 + quad * 8 + 2 * (i - 4));
            w1aT[i * 64 + tid] = f16x2{(f16)W1[2 * kk],     (f16)W1[2 * kk + 2]};
            w1bT[i * 64 + tid] = f16x2{(f16)W1[2 * kk + 1], (f16)W1[2 * kk + 3]};
            b1pT[i * 64 + tid] = f16x2{(f16)b1[kk],         (f16)b1[kk + 1]};
        }
        float* w3vT = (float*)(ws + WS_W3V);
        float* b2vT = (float*)(ws + WS_B2V);
        #pragma unroll
        for (int n = 0; n < 4; ++n) {
            w3vT[n * 64 + tid] = W3[n * 16 + nl];
            b2vT[n * 64 + tid] = b2[n * 16 + nl];
        }
    }
}

// block=256, min 3 waves/EU: reg budget ~170/wave (acc=64 AGPR + ~84 VGPR
// fits spill-free — R2 evidence; (256,4) forced 128 and spilled 380 MB).
__global__ __launch_bounds__(256, 3) void netc_kernel(
    const float* __restrict__ x,  const float* __restrict__ y,
    const float* __restrict__ ex, const float* __restrict__ ey,
    const unsigned char* __restrict__ ws,
    float* __restrict__ out)
{
    const int tid  = threadIdx.x;
    const int lane = tid & 63;
    const int wv   = tid >> 6;
    const int quad = lane >> 4;
    const int nl   = lane & 15;

    // ---------- preamble: ~40 fully-coalesced loads, no LDS ----------
    const float u_tgt = *(const float*)ws;   // wave-uniform -> scalar load
    const f16x8* bfragT = (const f16x8*)(ws + WS_BFRAG);
    f16x8 bfrag[4][2];
    #pragma unroll
    for (int n = 0; n < 4; ++n)
        #pragma unroll
        for (int ks = 0; ks < 2; ++ks)
            bfrag[n][ks] = bfragT[(n * 2 + ks) * 64 + lane];
    const f16x2* w1aT = (const f16x2*)(ws + WS_W1A);
    const f16x2* w1bT = (const f16x2*)(ws + WS_W1B);
    const f16x2* b1pT = (const f16x2*)(ws + WS_B1P);
    f16x2 w1a[8], w1b[8], b1p[8];
    #pragma unroll
    for (int i = 0; i < 8; ++i) {
        w1a[i] = w1aT[i * 64 + lane];
        w1b[i] = w1bT[i * 64 + lane];
        b1p[i] = b1pT[i * 64 + lane];
    }
    const float* w3vT = (const float*)(ws + WS_W3V);
    const float* b2vT = (const float*)(ws + WS_B2V);
    float w3v[4], b2v[4];
    #pragma unroll
    for (int n = 0; n < 4; ++n) { w3v[n] = w3vT[n * 64 + lane]; b2v[n] = b2vT[n * 64 + lane]; }

    const f16x2 zero2 = {(f16)0.f, (f16)0.f};
    const int nwaves = (gridDim.x * blockDim.x) >> 6;
    int chunk = (blockIdx.x << 2) + wv;

    // Gather loads in MFMA A-layout: lane reads element chunk*64 + t*16 + nl
    // (one 64B segment per load, 4-way quad broadcast). Lane-layout x,y for
    // the Hill math recovered with a 3-cndmask quad-select.
    float xg[4], yg[4], exg[4], eyg[4];
    if (chunk < NCHUNK) {
        #pragma unroll
        for (int t = 0; t < 4; ++t) {
            int a = chunk * 64 + t * 16 + nl;
            xg[t] = x[a]; yg[t] = y[a]; exg[t] = ex[a]; eyg[t] = ey[a];
        }
    }

    for (; chunk < NCHUNK; chunk += nwaves) {
        float ag[4], bg[4];
        #pragma unroll
        for (int t = 0; t < 4; ++t) { ag[t] = xg[t] + exg[t]; bg[t] = yg[t] + eyg[t]; }
        float cx0 = (quad & 1) ? xg[1] : xg[0];
        float cx1 = (quad & 1) ? xg[3] : xg[2];
        float cx  = (quad & 2) ? cx1 : cx0;
        float cy0 = (quad & 1) ? yg[1] : yg[0];
        float cy1 = (quad & 1) ? yg[3] : yg[2];
        float cy  = (quad & 2) ? cy1 : cy0;

        // prefetch next iter
        int nxt = chunk + nwaves;
        float nx_[4] = {0,0,0,0}, ny_[4] = {0,0,0,0}, nex_[4] = {0,0,0,0}, ney_[4] = {0,0,0,0};
        if (nxt < NCHUNK) {
            #pragma unroll
            for (int t = 0; t < 4; ++t) {
                int a = nxt * 64 + t * 16 + nl;
                nx_[t] = x[a]; ny_[t] = y[a]; nex_[t] = ex[a]; ney_[t] = ey[a];
            }
        }

        // accumulators pre-loaded with b2 (column-constant)
        f32x4 acc[4][4];
        #pragma unroll
        for (int t = 0; t < 4; ++t)
            #pragma unroll
            for (int n = 0; n < 4; ++n)
                acc[t][n] = f32x4{b2v[n], b2v[n], b2v[n], b2v[n]};

        #pragma unroll
        for (int t = 0; t < 4; ++t) {
            f16 ah = (f16)ag[t], bh = (f16)bg[t];
            f16x2 a2 = {ah, ah};
            f16x2 bb = {bh, bh};
            union { f16x2 h2[8]; f16x8 fr[2]; } u;
            #pragma unroll
            for (int i = 0; i < 8; ++i) {
                f16x2 h = a2 * w1a[i] + (bb * w1b[i] + b1p[i]);
                u.h2[i] = __builtin_elementwise_max(h, zero2);
            }
            #pragma unroll
            for (int n = 0; n < 4; ++n) {
                acc[t][n] = __builtin_amdgcn_mfma_f32_16x16x32_f16(u.fr[0], bfrag[n][0], acc[t][n], 0, 0, 0);
                acc[t][n] = __builtin_amdgcn_mfma_f32_16x16x32_f16(u.fr[1], bfrag[n][1], acc[t][n], 0, 0, 0);
            }
        }

        // ---------- epilogue: layer 3 via DPP row reductions ----------
        float uu[4][4];
        #pragma unroll
        for (int t = 0; t < 4; ++t)
            #pragma unroll
            for (int r = 0; r < 4; ++r) {
                float p = 0.f;
                #pragma unroll
                for (int n = 0; n < 4; ++n)
                    p = fmaf(fmaxf(acc[t][n][r], 0.f), w3v[n], p);
                p = dpp_add<0x128>(p);  // row_ror:8
                p = dpp_add<0x124>(p);  // row_ror:4
                p = dpp_add<0x122>(p);  // row_ror:2
                p = dpp_add<0x121>(p);  // row_ror:1
                uu[t][r] = p;
            }

        // sender lane s (p=s&15) provides uu[p>>2][p&3]
        float ur[4];
        #pragma unroll
        for (int t = 0; t < 4; ++t) {
            float v01 = (nl & 1) ? uu[t][1] : uu[t][0];
            float v23 = (nl & 1) ? uu[t][3] : uu[t][2];
            ur[t] = (nl & 2) ? v23 : v01;
        }
        float s01  = (nl & 4) ? ur[1] : ur[0];
        float s23  = (nl & 4) ? ur[3] : ur[2];
        float send = (nl & 8) ? s23 : s01;
        int srcLane = ((nl >> 2) << 4) + quad * 4 + (nl & 3);
        float u_e = __shfl(send, srcLane, 64) - u_tgt;

        // ---------- Hill kinetics (fp32) ----------
        float xs = cx * 0.1f, ys = cy * 0.1f;
        float x2 = xs * xs, y2 = ys * ys;
        float invx = __fdividef(1.0f, 0.25f + x2);
        float invy = __fdividef(1.0f, 0.25f + y2);
        float hx = x2 * invx, hy = y2 * invy;
        float gx = 0.25f * invx, gy = 0.25f * invy;
        float dx = 10.f * (fmaf(u_e, hx, hx) + 0.2f * gy - 1.1f * xs);
        float dy = 10.f * (hy + 0.2f * gx - 1.1f * ys);

        int e = chunk * 64 + lane;
        out[e]            = dx;
        out[BTOT + e]     = dy;
        out[2 * BTOT + e] = -dx;
        out[3 * BTOT + e] = -dy;

        #pragma unroll
        for (int t = 0; t < 4; ++t) {
            xg[t] = nx_[t]; yg[t] = ny_[t]; exg[t] = nex_[t]; eyg[t] = ney_[t];
        }
    }
}

extern "C" void kernel_launch(void* const* d_in, const int* in_sizes, int n_in,
                              void* d_out, int out_size, void* d_ws, size_t ws_size,
                              hipStream_t stream) {
    const float* x  = (const float*)d_in[0];
    const float* y  = (const float*)d_in[1];
    const float* ex = (const float*)d_in[2];
    const float* ey = (const float*)d_in[3];
    const float* W1 = (const float*)d_in[4];
    const float* b1 = (const float*)d_in[5];
    const float* W2 = (const float*)d_in[6];
    const float* b2 = (const float*)d_in[7];
    const float* W3 = (const float*)d_in[8];
    float* out = (float*)d_out;
    unsigned char* ws = (unsigned char*)d_ws;

    setup_kernel<<<1, 256, 0, stream>>>(W1, b1, W2, b2, W3, ws);
    // 768 blocks x 4 waves = 3072 waves = exactly 3 blocks/CU resident
    netc_kernel<<<768, 256, 0, stream>>>(x, y, ex, ey, ws, out);
}

// Round 5
// 129.211 us; speedup vs baseline: 1.5055x; 1.0268x over previous
//
#include <hip/hip_runtime.h>

#define BTOT 1000000

typedef _Float16 f16;
typedef f16 f16x2 __attribute__((ext_vector_type(2)));
typedef f16 f16x8 __attribute__((ext_vector_type(8)));
typedef float f32x2 __attribute__((ext_vector_type(2)));
typedef float f32x4 __attribute__((ext_vector_type(4)));

// d_ws layout (bytes) — written by setup_kernel, read coalesced by netc_kernel:
//   0     : float u_tgt
//   16    : bfragT[8][64]  f16x8   (8192 B)   item = n*2+ks
//   8208  : w1aT [8][64]   f16x2   (2048 B)
//   10256 : w1bT [8][64]   f16x2   (2048 B)
//   12304 : b1pT [8][64]   f16x2   (2048 B)
//   14352 : w3vT [4][64]   float   (1024 B)
//   15376 : b2vT [4][64]   float   (1024 B)
#define WS_BFRAG 16
#define WS_W1A   8208
#define WS_W1B   10256
#define WS_B1P   12304
#define WS_W3V   14352
#define WS_B2V   15376

// 16-lane-row rotate-and-add via DPP (VALU pipe, no LDS traffic).
template<int CTRL>
__device__ __forceinline__ float dpp_add(float v) {
    int pv = __builtin_amdgcn_update_dpp(0, __builtin_bit_cast(int, v),
                                         CTRL, 0xF, 0xF, true);
    return v + __builtin_bit_cast(float, pv);
}
__device__ __forceinline__ float row_reduce16(float p) {
    p = dpp_add<0x128>(p);  // row_ror:8
    p = dpp_add<0x124>(p);  // row_ror:4
    p = dpp_add<0x122>(p);  // row_ror:2
    p = dpp_add<0x121>(p);  // row_ror:1
    return p;
}

// One block. Stages W2 coalesced through padded LDS (conflict-free reads),
// computes u(target) once, emits per-lane register images into ws.
__global__ __launch_bounds__(256) void setup_kernel(
    const float* __restrict__ W1, const float* __restrict__ b1,
    const float* __restrict__ W2, const float* __restrict__ b2,
    const float* __restrict__ W3, unsigned char* __restrict__ ws)
{
    const int tid  = threadIdx.x;
    const int quad = (tid & 63) >> 4;
    const int nl   = tid & 15;

    __shared__ float w2s[64 * 65];   // padded: row stride 65 -> conflict-free
    __shared__ float h1s[64];
    __shared__ float part[4 * 64];

    const float4* W2v = (const float4*)W2;
    #pragma unroll
    for (int r = 0; r < 4; ++r) {
        int idx = r * 256 + tid;           // 1024 float4s total
        float4 f = W2v[idx];
        int g = idx * 4, row = g >> 6, col = g & 63;
        float* p = &w2s[row * 65 + col];
        p[0] = f.x; p[1] = f.y; p[2] = f.z; p[3] = f.w;
    }
    const float T = 6.2562059f;  // 0.62562059 * 10
    if (tid < 64)
        h1s[tid] = fmaxf(0.f, W1[2 * tid] * T + W1[2 * tid + 1] * T + b1[tid]);
    __syncthreads();

    {
        int r = tid & 63, kq = tid >> 6;
        float p = 0.f;
        #pragma unroll
        for (int k = 0; k < 16; ++k)
            p = fmaf(w2s[r * 65 + kq * 16 + k], h1s[kq * 16 + k], p);
        part[kq * 64 + r] = p;
    }
    __syncthreads();
    if (tid < 64) {
        float h2 = b2[tid] + part[tid] + part[64 + tid] + part[128 + tid] + part[192 + tid];
        float pr = fmaxf(0.f, h2) * W3[tid];
        #pragma unroll
        for (int m = 1; m < 64; m <<= 1) pr += __shfl_xor(pr, m, 64);
        if (tid == 0) *(float*)ws = pr;
    }

    if (tid < 64) {   // lane = tid: build this lane's register images
        f16x8* bfragT = (f16x8*)(ws + WS_BFRAG);
        #pragma unroll
        for (int n = 0; n < 4; ++n)
            #pragma unroll
            for (int ks = 0; ks < 2; ++ks) {
                f16x8 f;
                #pragma unroll
                for (int j = 0; j < 8; ++j)
                    f[j] = (f16)w2s[(n * 16 + nl) * 65 + ks * 32 + quad * 8 + j];
                bfragT[(n * 2 + ks) * 64 + tid] = f;
            }
        f16x2* w1aT = (f16x2*)(ws + WS_W1A);
        f16x2* w1bT = (f16x2*)(ws + WS_W1B);
        f16x2* b1pT = (f16x2*)(ws + WS_B1P);
        #pragma unroll
        for (int i = 0; i < 8; ++i) {
            int kk = (i < 4) ? (quad * 8 + 2 * i) : (32 + quad * 8 + 2 * (i - 4));
            w1aT[i * 64 + tid] = f16x2{(f16)W1[2 * kk],     (f16)W1[2 * kk + 2]};
            w1bT[i * 64 + tid] = f16x2{(f16)W1[2 * kk + 1], (f16)W1[2 * kk + 3]};
            b1pT[i * 64 + tid] = f16x2{(f16)b1[kk],         (f16)b1[kk + 1]};
        }
        float* w3vT = (float*)(ws + WS_W3V);
        float* b2vT = (float*)(ws + WS_B2V);
        #pragma unroll
        for (int n = 0; n < 4; ++n) {
            w3vT[n * 64 + tid] = W3[n * 16 + nl];
            b2vT[n * 64 + tid] = b2[n * 16 + nl];
        }
    }
}

// (256,3): 148 unified regs/wave fits spill-free (R2/R4 evidence); (256,4) spilled.
__global__ __launch_bounds__(256, 3) void netc_kernel(
    const float* __restrict__ x,  const float* __restrict__ y,
    const float* __restrict__ ex, const float* __restrict__ ey,
    const unsigned char* __restrict__ ws,
    float* __restrict__ out)
{
    const int tid  = threadIdx.x;
    const int lane = tid & 63;
    const int wv   = tid >> 6;
    const int quad = lane >> 4;
    const int nl   = lane & 15;

    // ---------- preamble: fully-coalesced ws loads ----------
    const float u_tgt = *(const float*)ws;
    const float one_minus_ut = 1.0f - u_tgt;
    const f16x8* bfragT = (const f16x8*)(ws + WS_BFRAG);
    f16x8 bfrag[4][2];
    #pragma unroll
    for (int n = 0; n < 4; ++n)
        #pragma unroll
        for (int ks = 0; ks < 2; ++ks)
            bfrag[n][ks] = bfragT[(n * 2 + ks) * 64 + lane];
    const f16x2* w1aT = (const f16x2*)(ws + WS_W1A);
    const f16x2* w1bT = (const f16x2*)(ws + WS_W1B);
    const f16x2* b1pT = (const f16x2*)(ws + WS_B1P);
    f16x2 w1a[8], w1b[8], b1p[8];
    #pragma unroll
    for (int i = 0; i < 8; ++i) {
        w1a[i] = w1aT[i * 64 + lane];
        w1b[i] = w1bT[i * 64 + lane];
        b1p[i] = b1pT[i * 64 + lane];
    }
    const float* w3vT = (const float*)(ws + WS_W3V);
    const float* b2vT = (const float*)(ws + WS_B2V);
    float w3v[4], b2v[4];
    #pragma unroll
    for (int n = 0; n < 4; ++n) { w3v[n] = w3vT[n * 64 + lane]; b2v[n] = b2vT[n * 64 + lane]; }

    const f16x2 zero2 = {(f16)0.f, (f16)0.f};
    const int nwaves = (gridDim.x * blockDim.x) >> 6;
    const int estep  = nwaves << 6;
    // final u-distribution source lane (loop-invariant byte address)
    const int srcb = (((nl >> 2) << 4) + quad * 4 + (nl & 3)) << 2;

    int e = (((blockIdx.x << 2) + wv) << 6) + lane;   // element = lane layout

    float cx = 0.f, cy = 0.f, cex = 0.f, cey = 0.f;
    if (e < BTOT) { cx = x[e]; cy = y[e]; cex = ex[e]; cey = ey[e]; }

    for (; e < BTOT; e += estep) {
        // 1. prefetch next chunk FIRST (so later wait is vmcnt(stores), not 0)
        int pe = e + estep;
        float nx = 0.f, ny = 0.f, nex = 0.f, ney = 0.f;
        if (pe < BTOT) { nx = x[pe]; ny = y[pe]; nex = ex[pe]; ney = ey[pe]; }

        // 2. pack this lane's (a,b) as f16 pair (element e)
        float av = cx + cex, bv = cy + cey;
        f16x2 pab = {(f16)av, (f16)bv};
        int pv = __builtin_bit_cast(int, pab);

        // 3. Hill math early — cur x,y die here; dy needs no u -> store now
        float xs = cx * 0.1f, ys = cy * 0.1f;
        float x2 = xs * xs, y2 = ys * ys;
        float invx = __fdividef(1.0f, 0.25f + x2);
        float invy = __fdividef(1.0f, 0.25f + y2);
        float hx = x2 * invx, hy = y2 * invy;
        float gx = 0.25f * invx, gy = 0.25f * invy;
        float cdx = 10.f * hx;
        float base_dx = fmaf(cdx, one_minus_ut, fmaf(2.f, gy, -11.f * xs));
        float dy = fmaf(10.f, hy, fmaf(2.f, gx, -11.f * ys));
        out[BTOT + e]     = dy;
        out[3 * BTOT + e] = -dy;

        // 4. distribute A-pairs: tile t gets element e_base + t*16 + nl
        f16x2 pt[4];
        #pragma unroll
        for (int t = 0; t < 4; ++t)
            pt[t] = __builtin_bit_cast(f16x2,
                __builtin_amdgcn_ds_bpermute((t * 16 + nl) << 2, pv));

        // 5. acc init with b2
        f32x4 acc[4][4];
        #pragma unroll
        for (int t = 0; t < 4; ++t)
            #pragma unroll
            for (int n = 0; n < 4; ++n)
                acc[t][n] = f32x4{b2v[n], b2v[n], b2v[n], b2v[n]};

        // 6. layer 1 (packed f16) + layer 2 MFMAs
        #pragma unroll
        for (int t = 0; t < 4; ++t) {
            f16x2 a2 = {pt[t][0], pt[t][0]};
            f16x2 bb = {pt[t][1], pt[t][1]};
            union { f16x2 h2[8]; f16x8 fr[2]; } u;
            #pragma unroll
            for (int i = 0; i < 8; ++i) {
                f16x2 h = a2 * w1a[i] + (bb * w1b[i] + b1p[i]);
                u.h2[i] = __builtin_elementwise_max(h, zero2);
            }
            #pragma unroll
            for (int n = 0; n < 4; ++n) {
                acc[t][n] = __builtin_amdgcn_mfma_f32_16x16x32_f16(u.fr[0], bfrag[n][0], acc[t][n], 0, 0, 0);
                acc[t][n] = __builtin_amdgcn_mfma_f32_16x16x32_f16(u.fr[1], bfrag[n][1], acc[t][n], 0, 0, 0);
            }
        }

        // 7. rotate cur <- prefetch (waits only the loads; stores already issued)
        cx = nx; cy = ny; cex = nex; cey = ney;

        // 8. epilogue: relu + w3 fma as packed f32 pairs, then DPP row reduce
        float uu[4][4];
        #pragma unroll
        for (int t = 0; t < 4; ++t) {
            f32x2 p01 = {0.f, 0.f}, p23 = {0.f, 0.f};
            #pragma unroll
            for (int n = 0; n < 4; ++n) {
                f32x2 lo = {acc[t][n][0], acc[t][n][1]};
                f32x2 hi = {acc[t][n][2], acc[t][n][3]};
                lo = __builtin_elementwise_max(lo, f32x2{0.f, 0.f});
                hi = __builtin_elementwise_max(hi, f32x2{0.f, 0.f});
                f32x2 w = {w3v[n], w3v[n]};
                p01 += lo * w;
                p23 += hi * w;
            }
            uu[t][0] = row_reduce16(p01[0]);
            uu[t][1] = row_reduce16(p01[1]);
            uu[t][2] = row_reduce16(p23[0]);
            uu[t][3] = row_reduce16(p23[1]);
        }

        // sender lane s (p=s&15) provides uu[p>>2][p&3]
        float ur[4];
        #pragma unroll
        for (int t = 0; t < 4; ++t) {
            float v01 = (nl & 1) ? uu[t][1] : uu[t][0];
            float v23 = (nl & 1) ? uu[t][3] : uu[t][2];
            ur[t] = (nl & 2) ? v23 : v01;
        }
        float s01  = (nl & 4) ? ur[1] : ur[0];
        float s23  = (nl & 4) ? ur[3] : ur[2];
        float send = (nl & 8) ? s23 : s01;
        float u_raw = __builtin_bit_cast(float,
            __builtin_amdgcn_ds_bpermute(srcb, __builtin_bit_cast(int, send)));

        // 9. dx tail + stores (u_tgt already folded into base_dx)
        float dx = fmaf(cdx, u_raw, base_dx);
        out[e]            = dx;
        out[2 * BTOT + e] = -dx;
    }
}

extern "C" void kernel_launch(void* const* d_in, const int* in_sizes, int n_in,
                              void* d_out, int out_size, void* d_ws, size_t ws_size,
                              hipStream_t stream) {
    const float* x  = (const float*)d_in[0];
    const float* y  = (const float*)d_in[1];
    const float* ex = (const float*)d_in[2];
    const float* ey = (const float*)d_in[3];
    const float* W1 = (const float*)d_in[4];
    const float* b1 = (const float*)d_in[5];
    const float* W2 = (const float*)d_in[6];
    const float* b2 = (const float*)d_in[7];
    const float* W3 = (const float*)d_in[8];
    float* out = (float*)d_out;
    unsigned char* ws = (unsigned char*)d_ws;

    setup_kernel<<<1, 256, 0, stream>>>(W1, b1, W2, b2, W3, ws);
    // 768 blocks x 4 waves = 3072 waves = exactly 3 blocks/CU resident
    netc_kernel<<<768, 256, 0, stream>>>(x, y, ex, ey, ws, out);
}

// Round 6
// 102.531 us; speedup vs baseline: 1.8972x; 1.2602x over previous
//
#include <hip/hip_runtime.h>

#define BTOT 1000000

typedef _Float16 f16;
typedef f16 f16x2 __attribute__((ext_vector_type(2)));
typedef f16 f16x8 __attribute__((ext_vector_type(8)));
typedef float f32x2 __attribute__((ext_vector_type(2)));
typedef float f32x4 __attribute__((ext_vector_type(4)));

// d_ws layout (bytes) — written by setup_kernel, read coalesced by netc_kernel:
//   0     : float u_tgt
//   16    : bfragT[8][64]  f16x8   (8192 B)   item = n*2+ks
//   8208  : w1aT [8][64]   f16x2   (2048 B)
//   10256 : w1bT [8][64]   f16x2   (2048 B)
//   12304 : b1pT [8][64]   f16x2   (2048 B)
//   14352 : w3vT [4][64]   float   (1024 B)
//   15376 : b2vT [4][64]   float   (1024 B)
#define WS_BFRAG 16
#define WS_W1A   8208
#define WS_W1B   10256
#define WS_B1P   12304
#define WS_W3V   14352
#define WS_B2V   15376

// 16-lane-row rotate-and-add via DPP (VALU pipe, no LDS traffic).
template<int CTRL>
__device__ __forceinline__ float dpp_add(float v) {
    int pv = __builtin_amdgcn_update_dpp(0, __builtin_bit_cast(int, v),
                                         CTRL, 0xF, 0xF, true);
    return v + __builtin_bit_cast(float, pv);
}
__device__ __forceinline__ float row_reduce16(float p) {
    p = dpp_add<0x128>(p);  // row_ror:8
    p = dpp_add<0x124>(p);  // row_ror:4
    p = dpp_add<0x122>(p);  // row_ror:2
    p = dpp_add<0x121>(p);  // row_ror:1
    return p;
}

// One block. Stages W2 coalesced through padded LDS (conflict-free reads),
// computes u(target) once, emits per-lane register images into ws.
__global__ __launch_bounds__(256) void setup_kernel(
    const float* __restrict__ W1, const float* __restrict__ b1,
    const float* __restrict__ W2, const float* __restrict__ b2,
    const float* __restrict__ W3, unsigned char* __restrict__ ws)
{
    const int tid  = threadIdx.x;
    const int quad = (tid & 63) >> 4;
    const int nl   = tid & 15;

    __shared__ float w2s[64 * 65];   // padded: row stride 65 -> conflict-free
    __shared__ float h1s[64];
    __shared__ float part[4 * 64];

    const float4* W2v = (const float4*)W2;
    #pragma unroll
    for (int r = 0; r < 4; ++r) {
        int idx = r * 256 + tid;           // 1024 float4s total
        float4 f = W2v[idx];
        int g = idx * 4, row = g >> 6, col = g & 63;
        float* p = &w2s[row * 65 + col];
        p[0] = f.x; p[1] = f.y; p[2] = f.z; p[3] = f.w;
    }
    const float T = 6.2562059f;  // 0.62562059 * 10
    if (tid < 64)
        h1s[tid] = fmaxf(0.f, W1[2 * tid] * T + W1[2 * tid + 1] * T + b1[tid]);
    __syncthreads();

    {
        int r = tid & 63, kq = tid >> 6;
        float p = 0.f;
        #pragma unroll
        for (int k = 0; k < 16; ++k)
            p = fmaf(w2s[r * 65 + kq * 16 + k], h1s[kq * 16 + k], p);
        part[kq * 64 + r] = p;
    }
    __syncthreads();
    if (tid < 64) {
        float h2 = b2[tid] + part[tid] + part[64 + tid] + part[128 + tid] + part[192 + tid];
        float pr = fmaxf(0.f, h2) * W3[tid];
        #pragma unroll
        for (int m = 1; m < 64; m <<= 1) pr += __shfl_xor(pr, m, 64);
        if (tid == 0) *(float*)ws = pr;
    }

    if (tid < 64) {   // lane = tid: build this lane's register images
        f16x8* bfragT = (f16x8*)(ws + WS_BFRAG);
        #pragma unroll
        for (int n = 0; n < 4; ++n)
            #pragma unroll
            for (int ks = 0; ks < 2; ++ks) {
                f16x8 f;
                #pragma unroll
                for (int j = 0; j < 8; ++j)
                    f[j] = (f16)w2s[(n * 16 + nl) * 65 + ks * 32 + quad * 8 + j];
                bfragT[(n * 2 + ks) * 64 + tid] = f;
            }
        f16x2* w1aT = (f16x2*)(ws + WS_W1A);
        f16x2* w1bT = (f16x2*)(ws + WS_W1B);
        f16x2* b1pT = (f16x2*)(ws + WS_B1P);
        #pragma unroll
        for (int i = 0; i < 8; ++i) {
            int kk = (i < 4) ? (quad * 8 + 2 * i) : (32 + quad * 8 + 2 * (i - 4));
            w1aT[i * 64 + tid] = f16x2{(f16)W1[2 * kk],     (f16)W1[2 * kk + 2]};
            w1bT[i * 64 + tid] = f16x2{(f16)W1[2 * kk + 1], (f16)W1[2 * kk + 3]};
            b1pT[i * 64 + tid] = f16x2{(f16)b1[kk],         (f16)b1[kk + 1]};
        }
        float* w3vT = (float*)(ws + WS_W3V);
        float* b2vT = (float*)(ws + WS_B2V);
        #pragma unroll
        for (int n = 0; n < 4; ++n) {
            w3vT[n * 64 + tid] = W3[n * 16 + nl];
            b2vT[n * 64 + tid] = b2[n * 16 + nl];
        }
    }
}

// (256,4): per-tile epilogue shrinks live state to ~115 regs -> fits 128/wave
// (R3 spilled because the old structure needed 148; spill tell = hbm_bytes).
__global__ __launch_bounds__(256, 4) void netc_kernel(
    const float* __restrict__ x,  const float* __restrict__ y,
    const float* __restrict__ ex, const float* __restrict__ ey,
    const unsigned char* __restrict__ ws,
    float* __restrict__ out)
{
    const int tid  = threadIdx.x;
    const int lane = tid & 63;
    const int wv   = tid >> 6;
    const int quad = lane >> 4;
    const int nl   = lane & 15;

    // ---------- preamble: fully-coalesced ws loads ----------
    const float u_tgt = *(const float*)ws;
    const float one_minus_ut = 1.0f - u_tgt;
    const f16x8* bfragT = (const f16x8*)(ws + WS_BFRAG);
    f16x8 bfrag[4][2];
    #pragma unroll
    for (int n = 0; n < 4; ++n)
        #pragma unroll
        for (int ks = 0; ks < 2; ++ks)
            bfrag[n][ks] = bfragT[(n * 2 + ks) * 64 + lane];
    const f16x2* w1aT = (const f16x2*)(ws + WS_W1A);
    const f16x2* w1bT = (const f16x2*)(ws + WS_W1B);
    const f16x2* b1pT = (const f16x2*)(ws + WS_B1P);
    f16x2 w1a[8], w1b[8], b1p[8];
    #pragma unroll
    for (int i = 0; i < 8; ++i) {
        w1a[i] = w1aT[i * 64 + lane];
        w1b[i] = w1bT[i * 64 + lane];
        b1p[i] = b1pT[i * 64 + lane];
    }
    const float* w3vT = (const float*)(ws + WS_W3V);
    const float* b2vT = (const float*)(ws + WS_B2V);
    float w3v[4], b2v[4];
    #pragma unroll
    for (int n = 0; n < 4; ++n) { w3v[n] = w3vT[n * 64 + lane]; b2v[n] = b2vT[n * 64 + lane]; }

    const f16x2 zero2 = {(f16)0.f, (f16)0.f};
    const int nwaves = (gridDim.x * blockDim.x) >> 6;   // 4096
    const int estep  = nwaves << 6;
    const int srcb = (((nl >> 2) << 4) + quad * 4 + (nl & 3)) << 2;

    int e0 = (((blockIdx.x << 2) + wv) << 6) + lane;

    // double-buffered input registers; loads stay in flight 2 loop bodies
    float axv = 0.f, ayv = 0.f, aexv = 0.f, aeyv = 0.f;
    float bxv = 0.f, byv = 0.f, bexv = 0.f, beyv = 0.f;
    if (e0 < BTOT)         { axv = x[e0]; ayv = y[e0]; aexv = ex[e0]; aeyv = ey[e0]; }
    if (e0 + estep < BTOT) { int p = e0 + estep; bxv = x[p]; byv = y[p]; bexv = ex[p]; beyv = ey[p]; }

    auto body = [&](int ee, float& rx, float& ry, float& rex, float& rey) {
        // consume buffer (issued 2 bodies ago -> arrived), then refill it
        float cx = rx, cy = ry, cex = rex, cey = rey;
        int pe = ee + 2 * estep;
        if (pe < BTOT) { rx = x[pe]; ry = y[pe]; rex = ex[pe]; rey = ey[pe]; }

        float av = cx + cex, bv = cy + cey;
        f16x2 pab = {(f16)av, (f16)bv};
        int pv = __builtin_bit_cast(int, pab);

        // Hill math early — dy needs no u -> store now
        float xs = cx * 0.1f, ys = cy * 0.1f;
        float x2 = xs * xs, y2 = ys * ys;
        float invx = __fdividef(1.0f, 0.25f + x2);
        float invy = __fdividef(1.0f, 0.25f + y2);
        float hx = x2 * invx, hy = y2 * invy;
        float gx = 0.25f * invx, gy = 0.25f * invy;
        float cdx = 10.f * hx;
        float base_dx = fmaf(cdx, one_minus_ut, fmaf(2.f, gy, -11.f * xs));
        float dy = fmaf(10.f, hy, fmaf(2.f, gx, -11.f * ys));
        out[BTOT + ee]     = dy;
        out[3 * BTOT + ee] = -dy;

        // distribute A-pairs: tile t gets element ee_base + t*16 + nl
        f16x2 pt[4];
        #pragma unroll
        for (int t = 0; t < 4; ++t)
            pt[t] = __builtin_bit_cast(f16x2,
                __builtin_amdgcn_ds_bpermute((t * 16 + nl) << 2, pv));

        float ur[4];
        #pragma unroll
        for (int t = 0; t < 4; ++t) {
            // acc init with b2 (per-tile: only 16 live acc regs)
            f32x4 acc[4];
            #pragma unroll
            for (int n = 0; n < 4; ++n)
                acc[n] = f32x4{b2v[n], b2v[n], b2v[n], b2v[n]};

            f16x2 a2 = {pt[t][0], pt[t][0]};
            f16x2 bb = {pt[t][1], pt[t][1]};
            union { f16x2 h2[8]; f16x8 fr[2]; } u;
            #pragma unroll
            for (int i = 0; i < 8; ++i) {
                f16x2 h = a2 * w1a[i] + (bb * w1b[i] + b1p[i]);
                u.h2[i] = __builtin_elementwise_max(h, zero2);
            }
            #pragma unroll
            for (int n = 0; n < 4; ++n) {
                acc[n] = __builtin_amdgcn_mfma_f32_16x16x32_f16(u.fr[0], bfrag[n][0], acc[n], 0, 0, 0);
                acc[n] = __builtin_amdgcn_mfma_f32_16x16x32_f16(u.fr[1], bfrag[n][1], acc[n], 0, 0, 0);
            }

            // per-tile epilogue: relu + w3 (packed f32), DPP row reduce,
            // then fold the r-select immediately (keeps 1 reg per tile)
            f32x2 p01 = {0.f, 0.f}, p23 = {0.f, 0.f};
            #pragma unroll
            for (int n = 0; n < 4; ++n) {
                f32x2 lo = {acc[n][0], acc[n][1]};
                f32x2 hi = {acc[n][2], acc[n][3]};
                lo = __builtin_elementwise_max(lo, f32x2{0.f, 0.f});
                hi = __builtin_elementwise_max(hi, f32x2{0.f, 0.f});
                f32x2 w = {w3v[n], w3v[n]};
                p01 += lo * w;
                p23 += hi * w;
            }
            float u0 = row_reduce16(p01[0]);
            float u1 = row_reduce16(p01[1]);
            float u2 = row_reduce16(p23[0]);
            float u3 = row_reduce16(p23[1]);
            float v01 = (nl & 1) ? u1 : u0;
            float v23 = (nl & 1) ? u3 : u2;
            ur[t] = (nl & 2) ? v23 : v01;
        }

        // send = ur[(nl>>2)&3]; sender lane s holds u for elem ((s&15)>>2)*16+(s>>4)*4+(s&3)
        float s01  = (nl & 4) ? ur[1] : ur[0];
        float s23  = (nl & 4) ? ur[3] : ur[2];
        float send = (nl & 8) ? s23 : s01;
        float u_raw = __builtin_bit_cast(float,
            __builtin_amdgcn_ds_bpermute(srcb, __builtin_bit_cast(int, send)));

        float dx = fmaf(cdx, u_raw, base_dx);
        out[ee]            = dx;
        out[2 * BTOT + ee] = -dx;
    };

    for (int e = e0; e < BTOT; e += 2 * estep) {
        body(e, axv, ayv, aexv, aeyv);
        int e1 = e + estep;
        if (e1 < BTOT)
            body(e1, bxv, byv, bexv, beyv);
    }
}

extern "C" void kernel_launch(void* const* d_in, const int* in_sizes, int n_in,
                              void* d_out, int out_size, void* d_ws, size_t ws_size,
                              hipStream_t stream) {
    const float* x  = (const float*)d_in[0];
    const float* y  = (const float*)d_in[1];
    const float* ex = (const float*)d_in[2];
    const float* ey = (const float*)d_in[3];
    const float* W1 = (const float*)d_in[4];
    const float* b1 = (const float*)d_in[5];
    const float* W2 = (const float*)d_in[6];
    const float* b2 = (const float*)d_in[7];
    const float* W3 = (const float*)d_in[8];
    float* out = (float*)d_out;
    unsigned char* ws = (unsigned char*)d_ws;

    setup_kernel<<<1, 256, 0, stream>>>(W1, b1, W2, b2, W3, ws);
    // 1024 blocks x 4 waves = 4096 waves = 4 blocks/CU resident (needs <=128 regs/wave)
    netc_kernel<<<1024, 256, 0, stream>>>(x, y, ex, ey, ws, out);
}